// Round 10
// baseline (180.625 us; speedup 1.0000x reference)
//
#include <hip/hip_runtime.h>
#include <stdint.h>

typedef unsigned short ushort_t;
typedef __attribute__((ext_vector_type(8))) short s16x8;    // 8 x bf16 (4 VGPR)
typedef __attribute__((ext_vector_type(4))) float f32x4;
typedef __attribute__((ext_vector_type(16))) float f32x16;
typedef __attribute__((ext_vector_type(4))) unsigned int u32x4;

// ---------- helpers ----------
__device__ __forceinline__ unsigned short f2bf(float x) {
  union { float f; unsigned u; } a; a.f = x;
  unsigned r = a.u + 0x7fffu + ((a.u >> 16) & 1u);   // RNE
  return (unsigned short)(r >> 16);
}
__device__ __forceinline__ float bf2f(unsigned short u) {
  union { unsigned u; float f; } a; a.u = ((unsigned)u) << 16;
  return a.f;
}
// packed f32x2 -> bf16x2 (single inst; no builtin on gfx950 — T12 recipe)
__device__ __forceinline__ unsigned cvtpk(float lo, float hi) {
  unsigned r;
  asm("v_cvt_pk_bf16_f32 %0, %1, %2" : "=v"(r) : "v"(lo), "v"(hi));
  return r;
}
// async global->LDS 16B: dest = wave-uniform base + lane*16 (m104); source is per-lane.
__device__ __forceinline__ void gll16(const ushort_t* g, ushort_t* l) {
  __builtin_amdgcn_global_load_lds((const __attribute__((address_space(1))) void*)g,
                                   (__attribute__((address_space(3))) void*)l, 16, 0, 0);
}

// ---------- fused prep: x->bf16, build Wcat (bf16, zero-padded), W_cproj->bf16 ----------
__global__ __launch_bounds__(256) void prep(
    const float* __restrict__ x, ushort_t* __restrict__ xb,
    const float* __restrict__ aQ, const float* __restrict__ aK,
    const float* __restrict__ aV, const float* __restrict__ bQ,
    const float* __restrict__ bK, const float* __restrict__ bV,
    ushort_t* __restrict__ W,
    const float* __restrict__ Wc, ushort_t* __restrict__ Wcb) {
  const int bid = blockIdx.x, tid = threadIdx.x;
  if (bid < 8192) {                           // x -> bf16 (4 elems/thread)
    int idx = bid * 256 + tid;
    const float4 v = *(const float4*)(x + (size_t)idx * 4);
    ushort4 o;
    o.x = f2bf(v.x); o.y = f2bf(v.y); o.z = f2bf(v.z); o.w = f2bf(v.w);
    *(ushort4*)(xb + (size_t)idx * 4) = o;
  } else if (bid < 8192 + 12288) {            // Wcat build (1 elem/thread)
    int idx = (bid - 8192) * 256 + tid;
    int row = idx >> 11, col = idx & 2047;
    float v = 0.f;
    if (row < 96)        v = aQ[row * 2048 + col];
    else if (row < 128)  v = aK[(row - 96) * 2048 + col];
    else if (row < 160)  v = aV[(row - 128) * 2048 + col];
    else if (row < 928)  v = bQ[(row - 160) * 2048 + col];
    else if (row < 1184) v = bK[(row - 928) * 2048 + col];
    else if (row < 1440) v = bV[(row - 1184) * 2048 + col];
    W[idx] = f2bf(v);
  } else {                                    // W_cproj -> bf16 (4 elems/thread)
    int idx = (bid - 8192 - 12288) * 256 + tid;
    const float4 v = *(const float4*)(Wc + (size_t)idx * 4);
    ushort4 o;
    o.x = f2bf(v.x); o.y = f2bf(v.y); o.z = f2bf(v.z); o.w = f2bf(v.w);
    *(ushort4*)(Wcb + (size_t)idx * 4) = o;
  }
}

// ---------- GEMM: C(MxN) = A(MxK bf16) * B(NxK bf16)^T; OutT = float or bf16 ----------
// m97 structure: 128x128 tile, BK=64, 4 waves, single 32KB LDS, global_load_lds.
template <typename OutT>
__global__ __launch_bounds__(256, 3) void gemm_bt(
    const ushort_t* __restrict__ A, const ushort_t* __restrict__ B,
    OutT* __restrict__ C, int M, int N, int K, int NT) {
  __shared__ ushort_t Asm[128 * 64];
  __shared__ ushort_t Bsm[128 * 64];
  const int bid = blockIdx.x;
  const int mt = bid / NT, nt = bid % NT;
  const int tid = threadIdx.x;
  const int lane = tid & 63;
  const int w = tid >> 6, wr = w >> 1, wc = w & 1;
  const int wbase = (tid & ~63);                 // wave-uniform chunk base

  f32x4 acc[4][4];
#pragma unroll
  for (int a1 = 0; a1 < 4; ++a1)
#pragma unroll
    for (int b1 = 0; b1 < 4; ++b1)
#pragma unroll
      for (int e = 0; e < 4; ++e) acc[a1][b1][e] = 0.f;

  const int nkt = K >> 6;

  auto STAGE = [&](int kt) {
#pragma unroll
    for (int i = 0; i < 4; ++i) {
      int g = i * 256 + tid;
      int row = g >> 3, sc = g & 7;
      int scc = sc ^ (row & 7);                  // pre-swizzled source column chunk
      gll16(A + (size_t)(mt * 128 + row) * K + kt * 64 + scc * 8,
            &Asm[(i * 256 + wbase) * 8]);
      gll16(B + (size_t)(nt * 128 + row) * K + kt * 64 + scc * 8,
            &Bsm[(i * 256 + wbase) * 8]);
    }
  };

  for (int kt = 0; kt < nkt; ++kt) {
    STAGE(kt);
    asm volatile("s_waitcnt vmcnt(0)" ::: "memory");
    __syncthreads();                             // tile ready for all waves
#pragma unroll
    for (int ks = 0; ks < 2; ++ks) {
      s16x8 af[4], bfv[4];
#pragma unroll
      for (int mi = 0; mi < 4; ++mi) {
        int row = wr * 64 + mi * 16 + (lane & 15);
        int colc = ks * 4 + (lane >> 4);
        af[mi] = *(const s16x8*)&Asm[(row * 8 + (colc ^ (row & 7))) * 8];
      }
#pragma unroll
      for (int ni = 0; ni < 4; ++ni) {
        int row = wc * 64 + ni * 16 + (lane & 15);
        int colc = ks * 4 + (lane >> 4);
        bfv[ni] = *(const s16x8*)&Bsm[(row * 8 + (colc ^ (row & 7))) * 8];
      }
#pragma unroll
      for (int mi = 0; mi < 4; ++mi)
#pragma unroll
        for (int ni = 0; ni < 4; ++ni)
          acc[mi][ni] = __builtin_amdgcn_mfma_f32_16x16x32_bf16(af[mi], bfv[ni], acc[mi][ni], 0, 0, 0);
    }
    __syncthreads();                             // all waves done reading before overwrite
  }
#pragma unroll
  for (int mi = 0; mi < 4; ++mi) {
    int row0 = mt * 128 + wr * 64 + mi * 16 + ((lane >> 4) << 2);
#pragma unroll
    for (int ni = 0; ni < 4; ++ni) {
      int col = nt * 128 + wc * 64 + ni * 16 + (lane & 15);
#pragma unroll
      for (int e = 0; e < 4; ++e) {
        if constexpr (sizeof(OutT) == 2)
          C[(size_t)(row0 + e) * N + col] = (OutT)f2bf(acc[mi][ni][e]);
        else
          C[(size_t)(row0 + e) * N + col] = (OutT)acc[mi][ni][e];
      }
    }
  }
}

// ---------- fuse: RoPE + rank contraction + RMSNorm -> q,k,v (B,H,T,D) bf16 ----------
// Cp is bf16 now. q additionally scaled by (1/sqrt(D))*log2(e) -> attention exp2.
__global__ __launch_bounds__(256) void fuse_qkv(
    const ushort_t* __restrict__ Cp, const float* __restrict__ cosT, const float* __restrict__ sinT,
    ushort_t* __restrict__ qb, ushort_t* __restrict__ kb, ushort_t* __restrict__ vb) {
  const int tok = blockIdx.x;             // 0..4095
  const int b = tok >> 11, t = tok & 2047;
  const ushort_t* __restrict__ row = Cp + (size_t)tok * 1536;
  __shared__ float aq[96], ak[32], av[32];
  __shared__ float rbq[768], rbk[256], bvs[256];
  __shared__ float cs[64], sn[64];
  const int tid = threadIdx.x;
  if (tid < 96)        aq[tid] = bf2f(row[tid]);
  else if (tid < 128)  ak[tid - 96] = bf2f(row[tid]);
  else if (tid < 160)  av[tid - 128] = bf2f(row[tid]);
  else if (tid < 224) { cs[tid - 160] = cosT[t * 64 + tid - 160];
                        sn[tid - 160] = sinT[t * 64 + tid - 160]; }
  __syncthreads();
  for (int p = tid; p < 384; p += 256) {      // rope b_q
    int r = p >> 6, d = p & 63;
    float x1 = bf2f(row[160 + r * 128 + d]), x2 = bf2f(row[160 + r * 128 + 64 + d]);
    rbq[r * 128 + d]      = x1 * cs[d] + x2 * sn[d];
    rbq[r * 128 + 64 + d] = x2 * cs[d] - x1 * sn[d];
  }
  if (tid < 128) {                            // rope b_k
    int r = tid >> 6, d = tid & 63;
    float x1 = bf2f(row[928 + r * 128 + d]), x2 = bf2f(row[928 + r * 128 + 64 + d]);
    rbk[r * 128 + d]      = x1 * cs[d] + x2 * sn[d];
    rbk[r * 128 + 64 + d] = x2 * cs[d] - x1 * sn[d];
  } else {                                    // copy b_v
    int p = tid - 128;
    bvs[p]       = bf2f(row[1184 + p]);
    bvs[p + 128] = bf2f(row[1184 + 128 + p]);
  }
  __syncthreads();
  const int w = tid >> 6, lane = tid & 63;
  const float QSC = 0.12751744154127828f;     // (1/sqrt(128)) * log2(e)
#pragma unroll
  for (int j = 0; j < 4; ++j) {               // q: 4 heads per wave
    int h = w + 4 * j;
    float q0 = 0.f, q1 = 0.f;
#pragma unroll
    for (int r = 0; r < 6; ++r) {
      float a = aq[r * 16 + h];
      q0 += a * rbq[r * 128 + lane];
      q1 += a * rbq[r * 128 + 64 + lane];
    }
    q0 *= (1.f / 6.f); q1 *= (1.f / 6.f);
    float ss = q0 * q0 + q1 * q1;
#pragma unroll
    for (int o = 32; o; o >>= 1) ss += __shfl_xor(ss, o);
    float rms = rsqrtf(ss * (1.f / 128.f) + 1.1920929e-7f) * QSC;
    size_t base = ((size_t)(b * 16 + h) * 2048 + t) * 128;
    qb[base + lane]      = f2bf(q0 * rms);
    qb[base + 64 + lane] = f2bf(q1 * rms);
  }
#pragma unroll
  for (int j = 0; j < 4; ++j) {               // k (norm) and v (no norm)
    int h = w + 4 * j;
    float k0 = ak[h] * rbk[lane]      + ak[16 + h] * rbk[128 + lane];
    float k1 = ak[h] * rbk[64 + lane] + ak[16 + h] * rbk[192 + lane];
    k0 *= 0.5f; k1 *= 0.5f;
    float ss = k0 * k0 + k1 * k1;
#pragma unroll
    for (int o = 32; o; o >>= 1) ss += __shfl_xor(ss, o);
    float rms = rsqrtf(ss * (1.f / 128.f) + 1.1920929e-7f);
    size_t base = ((size_t)(b * 16 + h) * 2048 + t) * 128;
    kb[base + lane]      = f2bf(k0 * rms);
    kb[base + 64 + lane] = f2bf(k1 * rms);
    float v0 = 0.5f * (av[h] * bvs[lane]      + av[16 + h] * bvs[128 + lane]);
    float v1 = 0.5f * (av[h] * bvs[64 + lane] + av[16 + h] * bvs[192 + lane]);
    vb[base + lane]      = f2bf(v0);
    vb[base + 64 + lane] = f2bf(v1);
  }
}

// ---------- V transpose: vb[bh][t][d] -> vt[bh][d][t] ----------
__global__ __launch_bounds__(256) void transpose_v(const ushort_t* __restrict__ src,
                                                   ushort_t* __restrict__ dst) {
  __shared__ ushort_t sm[64 * 128];     // 16B chunks, chunk = t*16 + (dc ^ (t&15))
  const int tt = blockIdx.x, bh = blockIdx.y;
  const size_t base = (size_t)bh * (2048 * 128);
  const int tid = threadIdx.x;
#pragma unroll
  for (int it = 0; it < 4; ++it) {
    int c = it * 256 + tid;
    int t = c >> 4, dc = c & 15;
    u32x4 v = *(const u32x4*)(src + base + (size_t)(tt * 64 + t) * 128 + dc * 8);
    *(u32x4*)&sm[(t * 16 + (dc ^ (t & 15))) * 8] = v;
  }
  __syncthreads();
#pragma unroll
  for (int it = 0; it < 4; ++it) {
    int c = it * 256 + tid;
    int d = c >> 3, tc = c & 7;
    ushort_t tmp[8];
#pragma unroll
    for (int jj = 0; jj < 8; ++jj) {
      int t = tc * 8 + jj;
      tmp[jj] = sm[(t * 16 + ((d >> 3) ^ (t & 15))) * 8 + (d & 7)];
    }
    *(u32x4*)(dst + base + (size_t)d * 2048 + tt * 64 + tc * 8) = *(const u32x4*)tmp;
  }
}

// ---------- causal flash attention: 4 waves, Q-tile 128, KVBLK=64, 2-phase dbuf ----------
// Round-7 proven config + tree-reassociated softmax row-sum (cuts 64-cyc dep chain).
__global__ __launch_bounds__(256, 2) void attn(
    const ushort_t* __restrict__ Q, const ushort_t* __restrict__ Kt,
    const ushort_t* __restrict__ VT, ushort_t* __restrict__ Y,
    ushort_t* __restrict__ Ppart, float* __restrict__ Spart) {
  static const signed char T1QT[16] = {15,15,14,14,13,13,12,12,11,11,10,10, 9, 9, 8, 7};
  static const signed char T1LO[16] = { 0, 9, 0, 9, 0, 9, 0, 9, 0, 9, 0, 9, 0, 9, 0, 0};
  static const signed char T1HI[16] = { 9,16, 9,15, 9,14, 9,13, 9,12, 9,11, 9,10, 9, 8};
  static const signed char T1MD[16] = { 1, 2, 1, 2, 1, 2, 1, 2, 1, 2, 1, 2, 1, 2, 0, 0};
  static const signed char T2QT[16] = {-1, 0,-1, 1,-1, 2,-1, 3,-1, 4,-1, 5,-1, 6,-1,-1};
  __shared__ ushort_t Ksm[2][64 * 128];      // 16 KB each, swizzled chunk^=(row&7)
  __shared__ ushort_t Vsm[2][128 * 64];      // 16 KB each, swizzled (V^T: rows=d, cols=kv)
  const int j = blockIdx.y, bh = blockIdx.x;
  const int b = bh >> 4, h = bh & 15;
  const int tid = threadIdx.x, lane = tid & 63, w = tid >> 6;
  const int hi = lane >> 5, li = lane & 31;
  const int wbase = (tid & ~63);
  const size_t hbase = (size_t)bh * (2048 * 128);

  auto STAGE = [&](int buf, int kv0s) {
#pragma unroll
    for (int it = 0; it < 4; ++it) {         // K: 64 rows x 16 chunks
      int g = it * 256 + tid;
      int row = g >> 4, sc = g & 15;
      gll16(Kt + hbase + (size_t)(kv0s + row) * 128 + (sc ^ (row & 7)) * 8,
            &Ksm[buf][(it * 256 + wbase) * 8]);
    }
#pragma unroll
    for (int it = 0; it < 4; ++it) {         // V^T: 128 rows(d) x 8 chunks(kv)
      int g = it * 256 + tid;
      int d = g >> 3, sc = g & 7;
      gll16(VT + hbase + (size_t)d * 2048 + kv0s + (sc ^ (d & 7)) * 8,
            &Vsm[buf][(it * 256 + wbase) * 8]);
    }
  };

  for (int task = 0; task < 2; ++task) {
    int qt, klo, khi, mode;
    if (task == 0) {
      qt = T1QT[j]; klo = (int)T1LO[j] * 128; khi = (int)T1HI[j] * 128; mode = T1MD[j];
    } else {
      qt = T2QT[j]; if (qt < 0) break;
      klo = 0; khi = (qt + 1) * 128; mode = 0;
    }
    const int wq0 = qt * 128 + w * 32;
    const int i = wq0 + li;                  // this lane's q-row

    s16x8 qf[8];
    const ushort_t* qrow = Q + hbase + (size_t)i * 128 + hi * 8;
#pragma unroll
    for (int c = 0; c < 8; ++c) qf[c] = *(const s16x8*)(qrow + c * 16);

    f32x16 o[4];
#pragma unroll
    for (int dt = 0; dt < 4; ++dt)
#pragma unroll
      for (int e = 0; e < 16; ++e) o[dt][e] = 0.f;
    float ssum = 0.f;

    const int nt = (khi - klo) >> 6;
    STAGE(0, klo);
    asm volatile("s_waitcnt vmcnt(0)" ::: "memory");
    __syncthreads();
    int cur = 0;
    for (int t = 0; t < nt; ++t) {
      const int kv0 = klo + t * 64;
      if (t + 1 < nt) STAGE(cur ^ 1, kv0 + 64);   // prefetch next KV tile
#pragma unroll
      for (int s = 0; s < 2; ++s) {
        const int kvs = kv0 + s * 32;
        if (kvs < wq0 + 32) {                     // this 32-kv subtile is (partly) visible
          const int krow = s * 32 + li;
          s16x8 kf[8];
#pragma unroll
          for (int c = 0; c < 8; ++c)
            kf[c] = *(const s16x8*)&Ksm[cur][(krow * 16 + ((2 * c + hi) ^ (krow & 7))) * 8];
          f32x16 st;
#pragma unroll
          for (int e = 0; e < 16; ++e) st[e] = 0.f;
          __builtin_amdgcn_s_setprio(1);
#pragma unroll
          for (int c = 0; c < 8; ++c)
            st = __builtin_amdgcn_mfma_f32_32x32x16_bf16(kf[c], qf[c], st, 0, 0, 0);
          __builtin_amdgcn_s_setprio(0);
          float p[16];
          if (kvs == wq0) {                       // wave-uniform diagonal branch
#pragma unroll
            for (int r = 0; r < 16; ++r) {
              int jrow = kvs + (r & 3) + 8 * (r >> 2) + 4 * hi;  // kv index (C/D row map)
              float pv = exp2f(st[r]);
              p[r] = (jrow > i) ? 0.f : pv;
            }
          } else {
#pragma unroll
            for (int r = 0; r < 16; ++r) p[r] = exp2f(st[r]);
          }
          // tree-reassociated row-sum (breaks the 16-deep serial add chain)
          float l0 = (p[0] + p[1]) + (p[2] + p[3]);
          float l1 = (p[4] + p[5]) + (p[6] + p[7]);
          float l2 = (p[8] + p[9]) + (p[10] + p[11]);
          float l3 = (p[12] + p[13]) + (p[14] + p[15]);
          float ls = (l0 + l1) + (l2 + l3);
          unsigned xp[8];
#pragma unroll
          for (int q2 = 0; q2 < 8; ++q2) xp[q2] = cvtpk(p[2 * q2], p[2 * q2 + 1]);
#if __has_builtin(__builtin_amdgcn_permlane32_swap)
          {                                        // row-sum across halves, VALU-only
            union { float f; unsigned u; } lu; lu.f = ls;
            auto rr = __builtin_amdgcn_permlane32_swap(lu.u, lu.u, false, false);
            union { unsigned u; float f; } r0, r1; r0.u = rr[0]; r1.u = rr[1];
            ls = r0.f + r1.f;
          }
          ssum += ls;
          __builtin_amdgcn_s_setprio(1);
#pragma unroll
          for (int c2 = 0; c2 < 2; ++c2) {        // build P A-frag via permlane32_swap
            union { s16x8 v; unsigned u[4]; } pu;
            auto r0 = __builtin_amdgcn_permlane32_swap(xp[4 * c2],     xp[4 * c2 + 2], false, false);
            auto r1 = __builtin_amdgcn_permlane32_swap(xp[4 * c2 + 1], xp[4 * c2 + 3], false, false);
            pu.u[0] = r0[0]; pu.u[2] = r0[1];
            pu.u[1] = r1[0]; pu.u[3] = r1[1];
#pragma unroll
            for (int dt = 0; dt < 4; ++dt) {
              int d = dt * 32 + li;
              s16x8 vf = *(const s16x8*)&Vsm[cur][(d * 8 + ((4 * s + 2 * c2 + hi) ^ (d & 7))) * 8];
              o[dt] = __builtin_amdgcn_mfma_f32_32x32x16_bf16(pu.v, vf, o[dt], 0, 0, 0);
            }
          }
          __builtin_amdgcn_s_setprio(0);
#else
          ls += __shfl_xor(ls, 32);
          ssum += ls;
          unsigned xw[8];
#pragma unroll
          for (int q2 = 0; q2 < 8; ++q2) xw[q2] = (unsigned)__shfl_xor((int)xp[q2], 32);
          __builtin_amdgcn_s_setprio(1);
#pragma unroll
          for (int c2 = 0; c2 < 2; ++c2) {
            union { s16x8 v; unsigned u[4]; } pu;
            pu.u[0] = hi ? xw[4 * c2 + 2] : xp[4 * c2];
            pu.u[1] = hi ? xw[4 * c2 + 3] : xp[4 * c2 + 1];
            pu.u[2] = hi ? xp[4 * c2 + 2] : xw[4 * c2];
            pu.u[3] = hi ? xp[4 * c2 + 3] : xw[4 * c2 + 1];
#pragma unroll
            for (int dt = 0; dt < 4; ++dt) {
              int d = dt * 32 + li;
              s16x8 vf = *(const s16x8*)&Vsm[cur][(d * 8 + ((4 * s + 2 * c2 + hi) ^ (d & 7))) * 8];
              o[dt] = __builtin_amdgcn_mfma_f32_32x32x16_bf16(pu.v, vf, o[dt], 0, 0, 0);
            }
          }
          __builtin_amdgcn_s_setprio(0);
#endif
        }
      }
      asm volatile("s_waitcnt vmcnt(0)" ::: "memory");
      __syncthreads();
      cur ^= 1;
    }

    if (mode == 2) {
      ushort_t* Pb = Ppart + (size_t)(bh * 7 + qt - 9) * 16384;
      if (hi == 0) Spart[(((size_t)bh * 7 + qt - 9) * 2 + 1) * 128 + w * 32 + li] = ssum;
#pragma unroll
      for (int r = 0; r < 16; ++r) {
        int rr = (r & 3) + 8 * (r >> 2) + 4 * hi;
#pragma unroll
        for (int dt = 0; dt < 4; ++dt)
          Pb[(size_t)(w * 32 + rr) * 128 + dt * 32 + li] = f2bf(o[dt][r]);
      }
    } else {
      if (mode == 1 && hi == 0)
        Spart[(((size_t)bh * 7 + qt - 9) * 2 + 0) * 128 + w * 32 + li] = ssum;
#pragma unroll
      for (int r = 0; r < 16; ++r) {
        int rr = (r & 3) + 8 * (r >> 2) + 4 * hi;
        float rs = __shfl(ssum, rr);
        float inv = (mode == 0) ? 1.f / rs : 1.f;
        size_t yrow = (size_t)(b * 2048 + wq0 + rr);
#pragma unroll
        for (int dt = 0; dt < 4; ++dt)
          Y[yrow * 2048 + h * 128 + dt * 32 + li] = f2bf(o[dt][r] * inv);
      }
    }
  }
}

// ---------- combine split-kv partials for qt 9..15 ----------
__global__ __launch_bounds__(256) void combine(ushort_t* __restrict__ Y,
                                               const ushort_t* __restrict__ Ppart,
                                               const float* __restrict__ Spart) {
  const int qs = blockIdx.x, bh = blockIdx.y;    // qs = qt-9, qt in 9..15
  const int b = bh >> 4, h = bh & 15;
  const ushort_t* Pb = Ppart + (size_t)(bh * 7 + qs) * 16384;
  const float* s0 = Spart + ((size_t)bh * 7 + qs) * 256;
  const float* s1 = s0 + 128;
#pragma unroll
  for (int it = 0; it < 8; ++it) {
    int c = it * 256 + threadIdx.x;      // 2048 chunks of 8 halfwords
    int r = c >> 4, dc = c & 15;
    ushort_t* yp = Y + ((size_t)(b * 2048 + (qs + 9) * 128 + r)) * 2048 + h * 128 + dc * 8;
    u32x4 o0 = *(const u32x4*)yp;
    u32x4 o1 = *(const u32x4*)(Pb + (size_t)r * 128 + dc * 8);
    float inv = 1.f / (s0[r] + s1[r]);
    const ushort_t* a = (const ushort_t*)&o0;
    const ushort_t* bq = (const ushort_t*)&o1;
    ushort_t res[8];
#pragma unroll
    for (int e = 0; e < 8; ++e) res[e] = f2bf((bf2f(a[e]) + bf2f(bq[e])) * inv);
    *(u32x4*)yp = *(const u32x4*)res;
  }
}

// ---------- launch ----------
extern "C" void kernel_launch(void* const* d_in, const int* in_sizes, int n_in,
                              void* d_out, int out_size, void* d_ws, size_t ws_size,
                              hipStream_t stream) {
  const float* x    = (const float*)d_in[0];
  const float* cosT = (const float*)d_in[1];
  const float* sinT = (const float*)d_in[2];
  const float* W_aQ = (const float*)d_in[3];
  const float* W_bQ = (const float*)d_in[4];
  const float* W_aK = (const float*)d_in[5];
  const float* W_bK = (const float*)d_in[6];
  const float* W_aV = (const float*)d_in[7];
  const float* W_bV = (const float*)d_in[8];
  const float* W_c  = (const float*)d_in[9];
  float* out = (float*)d_out;

  char* ws = (char*)d_ws;
  ushort_t* xb    = (ushort_t*)(ws);                      // 16 MB (reused as yb)
  ushort_t* Wcat  = (ushort_t*)(ws + 16777216);           // 6.29 MB; Spart overlays after proj
  ushort_t* Wcb   = (ushort_t*)(ws + 23068672);           // 8.39 MB
  ushort_t* Cpb   = (ushort_t*)(ws + 31457280);           // 12.6 MB bf16 Cp; vt+Ppart overlay after
  ushort_t* qb    = (ushort_t*)(ws + 56623104);           // 16 MB
  ushort_t* kb    = (ushort_t*)(ws + 73400320);           // 16 MB
  ushort_t* vb    = (ushort_t*)(ws + 90177536);           // 16 MB (row-major V, dead after transpose)
  ushort_t* yb    = xb;
  ushort_t* vt    = (ushort_t*)(ws + 31457280);           // 16 MB: V^T [bh][d][t] (over dead Cpb)
  ushort_t* Ppart = (ushort_t*)(ws + 48234496);           // 7.2 MB: chunk1 partial O (qt 9-15)
  float*    Spart = (float*)   (ws + 16777216);           // 229 KB: partial sums (over dead Wcat)

  prep<<<24576, 256, 0, stream>>>(x, xb, W_aQ, W_aK, W_aV, W_bQ, W_bK, W_bV,
                                  Wcat, W_c, Wcb);                      // all bf16 prep

  gemm_bt<ushort_t><<<384, 256, 0, stream>>>(xb, Wcat, Cpb, 4096, 1536, 2048, 12); // proj (bf16 out)
  fuse_qkv<<<4096, 256, 0, stream>>>(Cpb, cosT, sinT, qb, kb, vb);      // rope+contract+norm
  transpose_v<<<dim3(32, 32), 256, 0, stream>>>(vb, vt);                // V -> V^T
  attn<<<dim3(32, 16), 256, 0, stream>>>(qb, kb, vt, yb, Ppart, Spart); // causal attention
  combine<<<dim3(7, 32), 256, 0, stream>>>(yb, Ppart, Spart);           // merge kv-split
  gemm_bt<float><<<512, 256, 0, stream>>>(yb, Wcb, out, 4096, 2048, 2048, 16); // output projection
}

// Round 11
// 177.889 us; speedup vs baseline: 1.0154x; 1.0154x over previous
//
#include <hip/hip_runtime.h>
#include <stdint.h>

typedef unsigned short ushort_t;
typedef __attribute__((ext_vector_type(8))) short s16x8;    // 8 x bf16 (4 VGPR)
typedef __attribute__((ext_vector_type(4))) float f32x4;
typedef __attribute__((ext_vector_type(16))) float f32x16;
typedef __attribute__((ext_vector_type(4))) unsigned int u32x4;

// ---------- helpers ----------
__device__ __forceinline__ unsigned short f2bf(float x) {
  union { float f; unsigned u; } a; a.f = x;
  unsigned r = a.u + 0x7fffu + ((a.u >> 16) & 1u);   // RNE
  return (unsigned short)(r >> 16);
}
__device__ __forceinline__ float bf2f(unsigned short u) {
  union { unsigned u; float f; } a; a.u = ((unsigned)u) << 16;
  return a.f;
}
// packed f32x2 -> bf16x2 (single inst; no builtin on gfx950 — T12 recipe)
__device__ __forceinline__ unsigned cvtpk(float lo, float hi) {
  unsigned r;
  asm("v_cvt_pk_bf16_f32 %0, %1, %2" : "=v"(r) : "v"(lo), "v"(hi));
  return r;
}
// async global->LDS 16B: dest = wave-uniform base + lane*16 (m104); source is per-lane.
__device__ __forceinline__ void gll16(const ushort_t* g, ushort_t* l) {
  __builtin_amdgcn_global_load_lds((const __attribute__((address_space(1))) void*)g,
                                   (__attribute__((address_space(3))) void*)l, 16, 0, 0);
}

// ---------- fused prep: x->bf16, build Wcat (bf16, zero-padded), W_cproj->bf16 ----------
__global__ __launch_bounds__(256) void prep(
    const float* __restrict__ x, ushort_t* __restrict__ xb,
    const float* __restrict__ aQ, const float* __restrict__ aK,
    const float* __restrict__ aV, const float* __restrict__ bQ,
    const float* __restrict__ bK, const float* __restrict__ bV,
    ushort_t* __restrict__ W,
    const float* __restrict__ Wc, ushort_t* __restrict__ Wcb) {
  const int bid = blockIdx.x, tid = threadIdx.x;
  if (bid < 8192) {                           // x -> bf16 (4 elems/thread)
    int idx = bid * 256 + tid;
    const float4 v = *(const float4*)(x + (size_t)idx * 4);
    ushort4 o;
    o.x = f2bf(v.x); o.y = f2bf(v.y); o.z = f2bf(v.z); o.w = f2bf(v.w);
    *(ushort4*)(xb + (size_t)idx * 4) = o;
  } else if (bid < 8192 + 12288) {            // Wcat build (1 elem/thread)
    int idx = (bid - 8192) * 256 + tid;
    int row = idx >> 11, col = idx & 2047;
    float v = 0.f;
    if (row < 96)        v = aQ[row * 2048 + col];
    else if (row < 128)  v = aK[(row - 96) * 2048 + col];
    else if (row < 160)  v = aV[(row - 128) * 2048 + col];
    else if (row < 928)  v = bQ[(row - 160) * 2048 + col];
    else if (row < 1184) v = bK[(row - 928) * 2048 + col];
    else if (row < 1440) v = bV[(row - 1184) * 2048 + col];
    W[idx] = f2bf(v);
  } else {                                    // W_cproj -> bf16 (4 elems/thread)
    int idx = (bid - 8192 - 12288) * 256 + tid;
    const float4 v = *(const float4*)(Wc + (size_t)idx * 4);
    ushort4 o;
    o.x = f2bf(v.x); o.y = f2bf(v.y); o.z = f2bf(v.z); o.w = f2bf(v.w);
    *(ushort4*)(Wcb + (size_t)idx * 4) = o;
  }
}

// ---------- GEMM: C(MxN) = A(MxK bf16) * B(NxK bf16)^T; OutT = float or bf16 ----------
// m97 structure: 128x128 tile, BK=64, 4 waves, single 32KB LDS, global_load_lds.
template <typename OutT>
__global__ __launch_bounds__(256, 3) void gemm_bt(
    const ushort_t* __restrict__ A, const ushort_t* __restrict__ B,
    OutT* __restrict__ C, int M, int N, int K, int NT) {
  __shared__ ushort_t Asm[128 * 64];
  __shared__ ushort_t Bsm[128 * 64];
  const int bid = blockIdx.x;
  const int mt = bid / NT, nt = bid % NT;
  const int tid = threadIdx.x;
  const int lane = tid & 63;
  const int w = tid >> 6, wr = w >> 1, wc = w & 1;
  const int wbase = (tid & ~63);                 // wave-uniform chunk base

  f32x4 acc[4][4];
#pragma unroll
  for (int a1 = 0; a1 < 4; ++a1)
#pragma unroll
    for (int b1 = 0; b1 < 4; ++b1)
#pragma unroll
      for (int e = 0; e < 4; ++e) acc[a1][b1][e] = 0.f;

  const int nkt = K >> 6;

  auto STAGE = [&](int kt) {
#pragma unroll
    for (int i = 0; i < 4; ++i) {
      int g = i * 256 + tid;
      int row = g >> 3, sc = g & 7;
      int scc = sc ^ (row & 7);                  // pre-swizzled source column chunk
      gll16(A + (size_t)(mt * 128 + row) * K + kt * 64 + scc * 8,
            &Asm[(i * 256 + wbase) * 8]);
      gll16(B + (size_t)(nt * 128 + row) * K + kt * 64 + scc * 8,
            &Bsm[(i * 256 + wbase) * 8]);
    }
  };

  for (int kt = 0; kt < nkt; ++kt) {
    STAGE(kt);
    asm volatile("s_waitcnt vmcnt(0)" ::: "memory");
    __syncthreads();                             // tile ready for all waves
#pragma unroll
    for (int ks = 0; ks < 2; ++ks) {
      s16x8 af[4], bfv[4];
#pragma unroll
      for (int mi = 0; mi < 4; ++mi) {
        int row = wr * 64 + mi * 16 + (lane & 15);
        int colc = ks * 4 + (lane >> 4);
        af[mi] = *(const s16x8*)&Asm[(row * 8 + (colc ^ (row & 7))) * 8];
      }
#pragma unroll
      for (int ni = 0; ni < 4; ++ni) {
        int row = wc * 64 + ni * 16 + (lane & 15);
        int colc = ks * 4 + (lane >> 4);
        bfv[ni] = *(const s16x8*)&Bsm[(row * 8 + (colc ^ (row & 7))) * 8];
      }
#pragma unroll
      for (int mi = 0; mi < 4; ++mi)
#pragma unroll
        for (int ni = 0; ni < 4; ++ni)
          acc[mi][ni] = __builtin_amdgcn_mfma_f32_16x16x32_bf16(af[mi], bfv[ni], acc[mi][ni], 0, 0, 0);
    }
    __syncthreads();                             // all waves done reading before overwrite
  }
#pragma unroll
  for (int mi = 0; mi < 4; ++mi) {
    int row0 = mt * 128 + wr * 64 + mi * 16 + ((lane >> 4) << 2);
#pragma unroll
    for (int ni = 0; ni < 4; ++ni) {
      int col = nt * 128 + wc * 64 + ni * 16 + (lane & 15);
#pragma unroll
      for (int e = 0; e < 4; ++e) {
        if constexpr (sizeof(OutT) == 2)
          C[(size_t)(row0 + e) * N + col] = (OutT)f2bf(acc[mi][ni][e]);
        else
          C[(size_t)(row0 + e) * N + col] = (OutT)acc[mi][ni][e];
      }
    }
  }
}

// ---------- fuse: RoPE + rank contraction + RMSNorm -> q,k,v (B,H,T,D) bf16 ----------
// Cp is bf16. q additionally scaled by (1/sqrt(D))*log2(e) -> attention exp2.
__global__ __launch_bounds__(256) void fuse_qkv(
    const ushort_t* __restrict__ Cp, const float* __restrict__ cosT, const float* __restrict__ sinT,
    ushort_t* __restrict__ qb, ushort_t* __restrict__ kb, ushort_t* __restrict__ vb) {
  const int tok = blockIdx.x;             // 0..4095
  const int b = tok >> 11, t = tok & 2047;
  const ushort_t* __restrict__ row = Cp + (size_t)tok * 1536;
  __shared__ float aq[96], ak[32], av[32];
  __shared__ float rbq[768], rbk[256], bvs[256];
  __shared__ float cs[64], sn[64];
  const int tid = threadIdx.x;
  if (tid < 96)        aq[tid] = bf2f(row[tid]);
  else if (tid < 128)  ak[tid - 96] = bf2f(row[tid]);
  else if (tid < 160)  av[tid - 128] = bf2f(row[tid]);
  else if (tid < 224) { cs[tid - 160] = cosT[t * 64 + tid - 160];
                        sn[tid - 160] = sinT[t * 64 + tid - 160]; }
  __syncthreads();
  for (int p = tid; p < 384; p += 256) {      // rope b_q
    int r = p >> 6, d = p & 63;
    float x1 = bf2f(row[160 + r * 128 + d]), x2 = bf2f(row[160 + r * 128 + 64 + d]);
    rbq[r * 128 + d]      = x1 * cs[d] + x2 * sn[d];
    rbq[r * 128 + 64 + d] = x2 * cs[d] - x1 * sn[d];
  }
  if (tid < 128) {                            // rope b_k
    int r = tid >> 6, d = tid & 63;
    float x1 = bf2f(row[928 + r * 128 + d]), x2 = bf2f(row[928 + r * 128 + 64 + d]);
    rbk[r * 128 + d]      = x1 * cs[d] + x2 * sn[d];
    rbk[r * 128 + 64 + d] = x2 * cs[d] - x1 * sn[d];
  } else {                                    // copy b_v
    int p = tid - 128;
    bvs[p]       = bf2f(row[1184 + p]);
    bvs[p + 128] = bf2f(row[1184 + 128 + p]);
  }
  __syncthreads();
  const int w = tid >> 6, lane = tid & 63;
  const float QSC = 0.12751744154127828f;     // (1/sqrt(128)) * log2(e)
#pragma unroll
  for (int j = 0; j < 4; ++j) {               // q: 4 heads per wave
    int h = w + 4 * j;
    float q0 = 0.f, q1 = 0.f;
#pragma unroll
    for (int r = 0; r < 6; ++r) {
      float a = aq[r * 16 + h];
      q0 += a * rbq[r * 128 + lane];
      q1 += a * rbq[r * 128 + 64 + lane];
    }
    q0 *= (1.f / 6.f); q1 *= (1.f / 6.f);
    float ss = q0 * q0 + q1 * q1;
#pragma unroll
    for (int o = 32; o; o >>= 1) ss += __shfl_xor(ss, o);
    float rms = rsqrtf(ss * (1.f / 128.f) + 1.1920929e-7f) * QSC;
    size_t base = ((size_t)(b * 16 + h) * 2048 + t) * 128;
    qb[base + lane]      = f2bf(q0 * rms);
    qb[base + 64 + lane] = f2bf(q1 * rms);
  }
#pragma unroll
  for (int j = 0; j < 4; ++j) {               // k (norm) and v (no norm)
    int h = w + 4 * j;
    float k0 = ak[h] * rbk[lane]      + ak[16 + h] * rbk[128 + lane];
    float k1 = ak[h] * rbk[64 + lane] + ak[16 + h] * rbk[192 + lane];
    k0 *= 0.5f; k1 *= 0.5f;
    float ss = k0 * k0 + k1 * k1;
#pragma unroll
    for (int o = 32; o; o >>= 1) ss += __shfl_xor(ss, o);
    float rms = rsqrtf(ss * (1.f / 128.f) + 1.1920929e-7f);
    size_t base = ((size_t)(b * 16 + h) * 2048 + t) * 128;
    kb[base + lane]      = f2bf(k0 * rms);
    kb[base + 64 + lane] = f2bf(k1 * rms);
    float v0 = 0.5f * (av[h] * bvs[lane]      + av[16 + h] * bvs[128 + lane]);
    float v1 = 0.5f * (av[h] * bvs[64 + lane] + av[16 + h] * bvs[192 + lane]);
    vb[base + lane]      = f2bf(v0);
    vb[base + 64 + lane] = f2bf(v1);
  }
}

// ---------- V transpose: vb[bh][t][d] -> vt[bh][d][t] ----------
__global__ __launch_bounds__(256) void transpose_v(const ushort_t* __restrict__ src,
                                                   ushort_t* __restrict__ dst) {
  __shared__ ushort_t sm[64 * 128];     // 16B chunks, chunk = t*16 + (dc ^ (t&15))
  const int tt = blockIdx.x, bh = blockIdx.y;
  const size_t base = (size_t)bh * (2048 * 128);
  const int tid = threadIdx.x;
#pragma unroll
  for (int it = 0; it < 4; ++it) {
    int c = it * 256 + tid;
    int t = c >> 4, dc = c & 15;
    u32x4 v = *(const u32x4*)(src + base + (size_t)(tt * 64 + t) * 128 + dc * 8);
    *(u32x4*)&sm[(t * 16 + (dc ^ (t & 15))) * 8] = v;
  }
  __syncthreads();
#pragma unroll
  for (int it = 0; it < 4; ++it) {
    int c = it * 256 + tid;
    int d = c >> 3, tc = c & 7;
    ushort_t tmp[8];
#pragma unroll
    for (int jj = 0; jj < 8; ++jj) {
      int t = tc * 8 + jj;
      tmp[jj] = sm[(t * 16 + ((d >> 3) ^ (t & 15))) * 8 + (d & 7)];
    }
    *(u32x4*)(dst + base + (size_t)d * 2048 + tt * 64 + tc * 8) = *(const u32x4*)tmp;
  }
}

// ---------- causal flash attention: 4 waves, Q-tile 128, KVBLK=64, 2-phase dbuf ----------
// Round-9 proven config (59.5us): serial in-branch softmax sum (co-schedules with exp2),
// permlane32_swap P exchange, fixed-max exp2, 16 jobs/bh (512 blocks).
__global__ __launch_bounds__(256, 2) void attn(
    const ushort_t* __restrict__ Q, const ushort_t* __restrict__ Kt,
    const ushort_t* __restrict__ VT, ushort_t* __restrict__ Y,
    ushort_t* __restrict__ Ppart, float* __restrict__ Spart) {
  static const signed char T1QT[16] = {15,15,14,14,13,13,12,12,11,11,10,10, 9, 9, 8, 7};
  static const signed char T1LO[16] = { 0, 9, 0, 9, 0, 9, 0, 9, 0, 9, 0, 9, 0, 9, 0, 0};
  static const signed char T1HI[16] = { 9,16, 9,15, 9,14, 9,13, 9,12, 9,11, 9,10, 9, 8};
  static const signed char T1MD[16] = { 1, 2, 1, 2, 1, 2, 1, 2, 1, 2, 1, 2, 1, 2, 0, 0};
  static const signed char T2QT[16] = {-1, 0,-1, 1,-1, 2,-1, 3,-1, 4,-1, 5,-1, 6,-1,-1};
  __shared__ ushort_t Ksm[2][64 * 128];      // 16 KB each, swizzled chunk^=(row&7)
  __shared__ ushort_t Vsm[2][128 * 64];      // 16 KB each, swizzled (V^T: rows=d, cols=kv)
  const int j = blockIdx.y, bh = blockIdx.x;
  const int b = bh >> 4, h = bh & 15;
  const int tid = threadIdx.x, lane = tid & 63, w = tid >> 6;
  const int hi = lane >> 5, li = lane & 31;
  const int wbase = (tid & ~63);
  const size_t hbase = (size_t)bh * (2048 * 128);

  auto STAGE = [&](int buf, int kv0s) {
#pragma unroll
    for (int it = 0; it < 4; ++it) {         // K: 64 rows x 16 chunks
      int g = it * 256 + tid;
      int row = g >> 4, sc = g & 15;
      gll16(Kt + hbase + (size_t)(kv0s + row) * 128 + (sc ^ (row & 7)) * 8,
            &Ksm[buf][(it * 256 + wbase) * 8]);
    }
#pragma unroll
    for (int it = 0; it < 4; ++it) {         // V^T: 128 rows(d) x 8 chunks(kv)
      int g = it * 256 + tid;
      int d = g >> 3, sc = g & 7;
      gll16(VT + hbase + (size_t)d * 2048 + kv0s + (sc ^ (d & 7)) * 8,
            &Vsm[buf][(it * 256 + wbase) * 8]);
    }
  };

  for (int task = 0; task < 2; ++task) {
    int qt, klo, khi, mode;
    if (task == 0) {
      qt = T1QT[j]; klo = (int)T1LO[j] * 128; khi = (int)T1HI[j] * 128; mode = T1MD[j];
    } else {
      qt = T2QT[j]; if (qt < 0) break;
      klo = 0; khi = (qt + 1) * 128; mode = 0;
    }
    const int wq0 = qt * 128 + w * 32;
    const int i = wq0 + li;                  // this lane's q-row

    s16x8 qf[8];
    const ushort_t* qrow = Q + hbase + (size_t)i * 128 + hi * 8;
#pragma unroll
    for (int c = 0; c < 8; ++c) qf[c] = *(const s16x8*)(qrow + c * 16);

    f32x16 o[4];
#pragma unroll
    for (int dt = 0; dt < 4; ++dt)
#pragma unroll
      for (int e = 0; e < 16; ++e) o[dt][e] = 0.f;
    float ssum = 0.f;

    const int nt = (khi - klo) >> 6;
    STAGE(0, klo);
    asm volatile("s_waitcnt vmcnt(0)" ::: "memory");
    __syncthreads();
    int cur = 0;
    for (int t = 0; t < nt; ++t) {
      const int kv0 = klo + t * 64;
      if (t + 1 < nt) STAGE(cur ^ 1, kv0 + 64);   // prefetch next KV tile
#pragma unroll
      for (int s = 0; s < 2; ++s) {
        const int kvs = kv0 + s * 32;
        if (kvs < wq0 + 32) {                     // this 32-kv subtile is (partly) visible
          const int krow = s * 32 + li;
          s16x8 kf[8];
#pragma unroll
          for (int c = 0; c < 8; ++c)
            kf[c] = *(const s16x8*)&Ksm[cur][(krow * 16 + ((2 * c + hi) ^ (krow & 7))) * 8];
          f32x16 st;
#pragma unroll
          for (int e = 0; e < 16; ++e) st[e] = 0.f;
          __builtin_amdgcn_s_setprio(1);
#pragma unroll
          for (int c = 0; c < 8; ++c)
            st = __builtin_amdgcn_mfma_f32_32x32x16_bf16(kf[c], qf[c], st, 0, 0, 0);
          __builtin_amdgcn_s_setprio(0);
          float p[16]; float ls = 0.f;
          if (kvs == wq0) {                       // wave-uniform diagonal branch
#pragma unroll
            for (int r = 0; r < 16; ++r) {
              int jrow = kvs + (r & 3) + 8 * (r >> 2) + 4 * hi;  // kv index (C/D row map)
              float pv = exp2f(st[r]);
              p[r] = (jrow > i) ? 0.f : pv;
              ls += p[r];
            }
          } else {
#pragma unroll
            for (int r = 0; r < 16; ++r) { p[r] = exp2f(st[r]); ls += p[r]; }
          }
          unsigned xp[8];
#pragma unroll
          for (int q2 = 0; q2 < 8; ++q2) xp[q2] = cvtpk(p[2 * q2], p[2 * q2 + 1]);
#if __has_builtin(__builtin_amdgcn_permlane32_swap)
          {                                        // row-sum across halves, VALU-only
            union { float f; unsigned u; } lu; lu.f = ls;
            auto rr = __builtin_amdgcn_permlane32_swap(lu.u, lu.u, false, false);
            union { unsigned u; float f; } r0, r1; r0.u = rr[0]; r1.u = rr[1];
            ls = r0.f + r1.f;
          }
          ssum += ls;
          __builtin_amdgcn_s_setprio(1);
#pragma unroll
          for (int c2 = 0; c2 < 2; ++c2) {        // build P A-frag via permlane32_swap
            union { s16x8 v; unsigned u[4]; } pu;
            auto r0 = __builtin_amdgcn_permlane32_swap(xp[4 * c2],     xp[4 * c2 + 2], false, false);
            auto r1 = __builtin_amdgcn_permlane32_swap(xp[4 * c2 + 1], xp[4 * c2 + 3], false, false);
            pu.u[0] = r0[0]; pu.u[2] = r0[1];
            pu.u[1] = r1[0]; pu.u[3] = r1[1];
#pragma unroll
            for (int dt = 0; dt < 4; ++dt) {
              int d = dt * 32 + li;
              s16x8 vf = *(const s16x8*)&Vsm[cur][(d * 8 + ((4 * s + 2 * c2 + hi) ^ (d & 7))) * 8];
              o[dt] = __builtin_amdgcn_mfma_f32_32x32x16_bf16(pu.v, vf, o[dt], 0, 0, 0);
            }
          }
          __builtin_amdgcn_s_setprio(0);
#else
          ls += __shfl_xor(ls, 32);
          ssum += ls;
          unsigned xw[8];
#pragma unroll
          for (int q2 = 0; q2 < 8; ++q2) xw[q2] = (unsigned)__shfl_xor((int)xp[q2], 32);
          __builtin_amdgcn_s_setprio(1);
#pragma unroll
          for (int c2 = 0; c2 < 2; ++c2) {
            union { s16x8 v; unsigned u[4]; } pu;
            pu.u[0] = hi ? xw[4 * c2 + 2] : xp[4 * c2];
            pu.u[1] = hi ? xw[4 * c2 + 3] : xp[4 * c2 + 1];
            pu.u[2] = hi ? xp[4 * c2 + 2] : xw[4 * c2];
            pu.u[3] = hi ? xp[4 * c2 + 3] : xw[4 * c2 + 1];
#pragma unroll
            for (int dt = 0; dt < 4; ++dt) {
              int d = dt * 32 + li;
              s16x8 vf = *(const s16x8*)&Vsm[cur][(d * 8 + ((4 * s + 2 * c2 + hi) ^ (d & 7))) * 8];
              o[dt] = __builtin_amdgcn_mfma_f32_32x32x16_bf16(pu.v, vf, o[dt], 0, 0, 0);
            }
          }
          __builtin_amdgcn_s_setprio(0);
#endif
        }
      }
      asm volatile("s_waitcnt vmcnt(0)" ::: "memory");
      __syncthreads();
      cur ^= 1;
    }

    if (mode == 2) {
      ushort_t* Pb = Ppart + (size_t)(bh * 7 + qt - 9) * 16384;
      if (hi == 0) Spart[(((size_t)bh * 7 + qt - 9) * 2 + 1) * 128 + w * 32 + li] = ssum;
#pragma unroll
      for (int r = 0; r < 16; ++r) {
        int rr = (r & 3) + 8 * (r >> 2) + 4 * hi;
#pragma unroll
        for (int dt = 0; dt < 4; ++dt)
          Pb[(size_t)(w * 32 + rr) * 128 + dt * 32 + li] = f2bf(o[dt][r]);
      }
    } else {
      if (mode == 1 && hi == 0)
        Spart[(((size_t)bh * 7 + qt - 9) * 2 + 0) * 128 + w * 32 + li] = ssum;
#pragma unroll
      for (int r = 0; r < 16; ++r) {
        int rr = (r & 3) + 8 * (r >> 2) + 4 * hi;
        float rs = __shfl(ssum, rr);
        float inv = (mode == 0) ? 1.f / rs : 1.f;
        size_t yrow = (size_t)(b * 2048 + wq0 + rr);
#pragma unroll
        for (int dt = 0; dt < 4; ++dt)
          Y[yrow * 2048 + h * 128 + dt * 32 + li] = f2bf(o[dt][r] * inv);
      }
    }
  }
}

// ---------- combine split-kv partials for qt 9..15 ----------
__global__ __launch_bounds__(256) void combine(ushort_t* __restrict__ Y,
                                               const ushort_t* __restrict__ Ppart,
                                               const float* __restrict__ Spart) {
  const int qs = blockIdx.x, bh = blockIdx.y;    // qs = qt-9, qt in 9..15
  const int b = bh >> 4, h = bh & 15;
  const ushort_t* Pb = Ppart + (size_t)(bh * 7 + qs) * 16384;
  const float* s0 = Spart + ((size_t)bh * 7 + qs) * 256;
  const float* s1 = s0 + 128;
#pragma unroll
  for (int it = 0; it < 8; ++it) {
    int c = it * 256 + threadIdx.x;      // 2048 chunks of 8 halfwords
    int r = c >> 4, dc = c & 15;
    ushort_t* yp = Y + ((size_t)(b * 2048 + (qs + 9) * 128 + r)) * 2048 + h * 128 + dc * 8;
    u32x4 o0 = *(const u32x4*)yp;
    u32x4 o1 = *(const u32x4*)(Pb + (size_t)r * 128 + dc * 8);
    float inv = 1.f / (s0[r] + s1[r]);
    const ushort_t* a = (const ushort_t*)&o0;
    const ushort_t* bq = (const ushort_t*)&o1;
    ushort_t res[8];
#pragma unroll
    for (int e = 0; e < 8; ++e) res[e] = f2bf((bf2f(a[e]) + bf2f(bq[e])) * inv);
    *(u32x4*)yp = *(const u32x4*)res;
  }
}

// ---------- launch ----------
extern "C" void kernel_launch(void* const* d_in, const int* in_sizes, int n_in,
                              void* d_out, int out_size, void* d_ws, size_t ws_size,
                              hipStream_t stream) {
  const float* x    = (const float*)d_in[0];
  const float* cosT = (const float*)d_in[1];
  const float* sinT = (const float*)d_in[2];
  const float* W_aQ = (const float*)d_in[3];
  const float* W_bQ = (const float*)d_in[4];
  const float* W_aK = (const float*)d_in[5];
  const float* W_bK = (const float*)d_in[6];
  const float* W_aV = (const float*)d_in[7];
  const float* W_bV = (const float*)d_in[8];
  const float* W_c  = (const float*)d_in[9];
  float* out = (float*)d_out;

  char* ws = (char*)d_ws;
  ushort_t* xb    = (ushort_t*)(ws);                      // 16 MB (reused as yb)
  ushort_t* Wcat  = (ushort_t*)(ws + 16777216);           // 6.29 MB; Spart overlays after proj
  ushort_t* Wcb   = (ushort_t*)(ws + 23068672);           // 8.39 MB
  ushort_t* Cpb   = (ushort_t*)(ws + 31457280);           // 12.6 MB bf16 Cp; vt+Ppart overlay after
  ushort_t* qb    = (ushort_t*)(ws + 56623104);           // 16 MB
  ushort_t* kb    = (ushort_t*)(ws + 73400320);           // 16 MB
  ushort_t* vb    = (ushort_t*)(ws + 90177536);           // 16 MB (row-major V, dead after transpose)
  ushort_t* yb    = xb;
  ushort_t* vt    = (ushort_t*)(ws + 31457280);           // 16 MB: V^T [bh][d][t] (over dead Cpb)
  ushort_t* Ppart = (ushort_t*)(ws + 48234496);           // 7.2 MB: chunk1 partial O (qt 9-15)
  float*    Spart = (float*)   (ws + 16777216);           // 229 KB: partial sums (over dead Wcat)

  prep<<<24576, 256, 0, stream>>>(x, xb, W_aQ, W_aK, W_aV, W_bQ, W_bK, W_bV,
                                  Wcat, W_c, Wcb);                      // all bf16 prep

  gemm_bt<ushort_t><<<384, 256, 0, stream>>>(xb, Wcat, Cpb, 4096, 1536, 2048, 12); // proj (bf16 out)
  fuse_qkv<<<4096, 256, 0, stream>>>(Cpb, cosT, sinT, qb, kb, vb);      // rope+contract+norm
  transpose_v<<<dim3(32, 32), 256, 0, stream>>>(vb, vt);                // V -> V^T
  attn<<<dim3(32, 16), 256, 0, stream>>>(qb, kb, vt, yb, Ppart, Spart); // causal attention
  combine<<<dim3(7, 32), 256, 0, stream>>>(yb, Ppart, Spart);           // merge kv-split
  gemm_bt<float><<<512, 256, 0, stream>>>(yb, Wcb, out, 4096, 2048, 2048, 16); // output projection
}